// Round 2
// baseline (206.741 us; speedup 1.0000x reference)
//
#include <hip/hip_runtime.h>
#include <hip/hip_bf16.h>

#define NFEAT 50
#define EDIM 64
#define LN_EPS 1e-5f
#define NEG_INF_C (-1000000000.0f)

typedef __bf16 bf16_t;
typedef __bf16 bf16x8 __attribute__((ext_vector_type(8)));
typedef __bf16 bf16x4 __attribute__((ext_vector_type(4)));
typedef float f32x4 __attribute__((ext_vector_type(4)));

// ws layout (bf16 staging, produced by prep_kernel from fp32 inputs):
//   attnT: [T][64][64], attnT[t][g][f] = attn[t][f][g], zero padded (g>=50 or f>=50 -> 0)
//   WT:    [T][2][64][64], WT[t][i][e][k] = w0[t][i*64+k][e]  (B-operand ready: row e, contiguous k)

__global__ __launch_bounds__(256) void prep_kernel(
    const float* __restrict__ masker, const float* __restrict__ ln_w,
    const float* __restrict__ ln_b, const float* __restrict__ tw,
    bf16_t* __restrict__ ws_attnT, bf16_t* __restrict__ ws_WT)
{
  const int tid = threadIdx.x;
  const int lane = tid & 63;

  // ---- WT staging: 16 blocks x 256 threads x 4 elems = 16384 ----
  const int gidx = blockIdx.x * 256 + tid;
#pragma unroll
  for (int j = 0; j < 4; ++j) {
    int o = gidx * 4 + j;            // ((t*2+i)*64 + e)*64 + k
    int k = o & 63;
    int e = (o >> 6) & 63;
    int ti = o >> 12;                // t*2+i
    ws_WT[o] = (bf16_t)tw[(ti * 64 + k) * 64 + e];
  }

  // ---- attention columns: 128 tasks (t,g) over 64 waves, 2 each ----
  const int wg = blockIdx.x * 4 + (tid >> 6);  // 0..63
  const int f = lane;
  const bool fv = (f < NFEAT);
  for (int i = 0; i < 2; ++i) {
    int col = wg * 2 + i;            // 0..127
    int t = col >> 6, g = col & 63;
    float val = 0.f;
    if (fv && g < NFEAT) {
      float a0 = masker[((t * 3 + 0) * NFEAT + f) * NFEAT + g];
      float a1 = masker[((t * 3 + 1) * NFEAT + f) * NFEAT + g];
      float a2 = masker[((t * 3 + 2) * NFEAT + f) * NFEAT + g];
      float prod = a0 * a1 * a2;
      val = prod > 0.f ? prod : 0.f;            // relu
    }
    // mean/var over f (all 50 rows, zeros included)
    float s = val;
    for (int off = 32; off > 0; off >>= 1) s += __shfl_xor(s, off);
    float mean = s / (float)NFEAT;
    float d = fv ? (val - mean) : 0.f;
    float v2 = d * d;
    for (int off = 32; off > 0; off >>= 1) v2 += __shfl_xor(v2, off);
    float var = v2 / (float)NFEAT;
    float lw = fv ? ln_w[f] : 0.f;
    float lb = fv ? ln_b[f] : 0.f;
    float aln = d * rsqrtf(var + LN_EPS) * lw + lb;
    float logit = aln + ((val != 0.f) ? 0.f : NEG_INF_C) + ((f == g) ? 1.f : 0.f);
    if (!fv) logit = -3.0e38f;
    float mx = logit;
    for (int off = 32; off > 0; off >>= 1) mx = fmaxf(mx, __shfl_xor(mx, off));
    float ex = fv ? expf(logit - mx) : 0.f;
    float se = ex;
    for (int off = 32; off > 0; off >>= 1) se += __shfl_xor(se, off);
    float attn = (fv && g < NFEAT && val != 0.f) ? (ex / se) : 0.f;
    ws_attnT[(t * 64 + g) * 64 + f] = (bf16_t)attn;
  }
}

// One block per batch element b. 256 threads = 4 waves; wave w owns output rows 16w..16w+15.
__global__ __launch_bounds__(256) void main_kernel(
    const float* __restrict__ feat, const float* __restrict__ tb,
    const float* __restrict__ gw, const float* __restrict__ gb,
    const bf16_t* __restrict__ ws_attnT, const bf16_t* __restrict__ ws_WT,
    float* __restrict__ out)
{
  __shared__ bf16_t sPT[64 * 72];   // P^T[e][f'], pitch 72 (16B-aligned rows)
  __shared__ float sLog[2][4];

  const int tid = threadIdx.x;
  const int w = tid >> 6;
  const int lane = tid & 63;
  const int l16 = lane & 15;
  const int lquad = lane >> 4;
  const int m0 = w * 16;
  const int b = blockIdx.x;
  const float* featb = feat + b * (NFEAT * EDIM);

  f32x4 accH[2][4];

#pragma unroll
  for (int t = 0; t < 2; ++t) {
    f32x4 accP[4];
#pragma unroll
    for (int n = 0; n < 4; ++n) {
      accP[n] = (f32x4){0.f, 0.f, 0.f, 0.f};
      accH[t][n] = (f32x4){0.f, 0.f, 0.f, 0.f};
    }

    // ---- pass 1: accH = F@W1 (partial), accP = F@W2 ----
    const int fA = m0 + l16;                    // A row (feat row), zero if >= 50
#pragma unroll
    for (int kc = 0; kc < 2; ++kc) {
      bf16x8 a;
#pragma unroll
      for (int j = 0; j < 8; ++j) a[j] = (bf16_t)0.f;
      if (fA < NFEAT) {
        const float4* pa = (const float4*)(featb + fA * 64 + kc * 32 + lquad * 8);
        float4 x0 = pa[0], x1 = pa[1];
        a[0] = (bf16_t)x0.x; a[1] = (bf16_t)x0.y; a[2] = (bf16_t)x0.z; a[3] = (bf16_t)x0.w;
        a[4] = (bf16_t)x1.x; a[5] = (bf16_t)x1.y; a[6] = (bf16_t)x1.z; a[7] = (bf16_t)x1.w;
      }
#pragma unroll
      for (int n = 0; n < 4; ++n) {
        const bf16x8 b1 = *(const bf16x8*)(ws_WT + ((t * 2 + 0) * 64 + n * 16 + l16) * 64 + kc * 32 + lquad * 8);
        const bf16x8 b2 = *(const bf16x8*)(ws_WT + ((t * 2 + 1) * 64 + n * 16 + l16) * 64 + kc * 32 + lquad * 8);
        accH[t][n] = __builtin_amdgcn_mfma_f32_16x16x32_bf16(a, b1, accH[t][n], 0, 0, 0);
        accP[n]    = __builtin_amdgcn_mfma_f32_16x16x32_bf16(a, b2, accP[n], 0, 0, 0);
      }
    }

    // ---- write P^T to LDS (bf16) ----
#pragma unroll
    for (int n = 0; n < 4; ++n) {
      bf16x4 pv;
      pv[0] = (bf16_t)accP[n][0]; pv[1] = (bf16_t)accP[n][1];
      pv[2] = (bf16_t)accP[n][2]; pv[3] = (bf16_t)accP[n][3];
      *(bf16x4*)&sPT[(n * 16 + l16) * 72 + m0 + lquad * 4] = pv;
    }
    __syncthreads();

    // ---- pass 2: accH += C_t @ P   (A = attnT rows, B = P from LDS) ----
#pragma unroll
    for (int kc = 0; kc < 2; ++kc) {
      const bf16x8 a = *(const bf16x8*)(ws_attnT + (t * 64 + m0 + l16) * 64 + kc * 32 + lquad * 8);
#pragma unroll
      for (int n = 0; n < 4; ++n) {
        const bf16x8 bp = *(const bf16x8*)(&sPT[(n * 16 + l16) * 72 + kc * 32 + lquad * 8]);
        accH[t][n] = __builtin_amdgcn_mfma_f32_16x16x32_bf16(a, bp, accH[t][n], 0, 0, 0);
      }
    }

    // ---- + transform_b, gate-logit partial ----
    float p = 0.f;
#pragma unroll
    for (int n = 0; n < 4; ++n) {
      int e = n * 16 + l16;
#pragma unroll
      for (int r = 0; r < 4; ++r) {
        int f = m0 + lquad * 4 + r;
        if (f < NFEAT) {
          float hv = accH[t][n][r] + tb[(t * NFEAT + f) * 64 + e];
          accH[t][n][r] = hv;
          p += hv * gw[f * 64 + e];
        }
      }
    }
    for (int off = 32; off > 0; off >>= 1) p += __shfl_xor(p, off);
    if (lane == 0) sLog[t][w] = p;
    __syncthreads();   // t=0: also fences sPT reads before t=1 overwrites; t=1: sLog visible below
  }

  // ---- gate softmax over T=2, weighted sum, store ----
  const float gbv = gb[0];
  const float g0 = sLog[0][0] + sLog[0][1] + sLog[0][2] + sLog[0][3] + gbv;
  const float g1 = sLog[1][0] + sLog[1][1] + sLog[1][2] + sLog[1][3] + gbv;
  const float mx = fmaxf(g0, g1);
  const float e0 = expf(g0 - mx), e1 = expf(g1 - mx);
  const float inv = 1.f / (e0 + e1);
  const float ga0 = e0 * inv, ga1 = e1 * inv;

  float* outb = out + b * (NFEAT * EDIM);
#pragma unroll
  for (int n = 0; n < 4; ++n) {
    int e = n * 16 + l16;
#pragma unroll
    for (int r = 0; r < 4; ++r) {
      int f = m0 + lquad * 4 + r;
      if (f < NFEAT)
        outb[f * 64 + e] = ga0 * accH[0][n][r] + ga1 * accH[1][n][r];
    }
  }
}

extern "C" void kernel_launch(void* const* d_in, const int* in_sizes, int n_in,
                              void* d_out, int out_size, void* d_ws, size_t ws_size,
                              hipStream_t stream) {
  const float* feat   = (const float*)d_in[0];
  const float* masker = (const float*)d_in[1];
  const float* tw     = (const float*)d_in[2];
  const float* tb     = (const float*)d_in[3];
  const float* lnw    = (const float*)d_in[4];
  const float* lnb    = (const float*)d_in[5];
  const float* gw     = (const float*)d_in[6];
  const float* gb     = (const float*)d_in[7];
  float* out = (float*)d_out;

  bf16_t* ws_attnT = (bf16_t*)d_ws;                 // 2*64*64 = 8192 elems
  bf16_t* ws_WT    = ws_attnT + 2 * 64 * 64;        // 2*2*64*64 = 16384 elems

  prep_kernel<<<16, 256, 0, stream>>>(masker, lnw, lnb, tw, ws_attnT, ws_WT);
  main_kernel<<<4096, 256, 0, stream>>>(feat, tb, gw, gb, ws_attnT, ws_WT, out);
}

// Round 3
// 169.176 us; speedup vs baseline: 1.2220x; 1.2220x over previous
//
#include <hip/hip_runtime.h>
#include <hip/hip_bf16.h>

#define NFEAT 50
#define EDIM 64
#define LN_EPS 1e-5f
#define NEG_INF_C (-1000000000.0f)
#define NB 4

typedef __bf16 bf16_t;
typedef __bf16 bf16x8 __attribute__((ext_vector_type(8)));
typedef __bf16 bf16x4 __attribute__((ext_vector_type(4)));
typedef float f32x4 __attribute__((ext_vector_type(4)));

// ws layout (bf16 staging, produced by prep_kernel from fp32 inputs):
//   attnT: [T][64][64], attnT[t][g][f] = attn[t][f][g], zero padded (g>=50 or f>=50 -> 0)
//   WT:    [T][2][64][64], WT[t][i][e][k] = w0[t][i*64+k][e]  (B-operand ready: row e, contiguous k)

__global__ __launch_bounds__(256) void prep_kernel(
    const float* __restrict__ masker, const float* __restrict__ ln_w,
    const float* __restrict__ ln_b, const float* __restrict__ tw,
    bf16_t* __restrict__ ws_attnT, bf16_t* __restrict__ ws_WT)
{
  const int tid = threadIdx.x;
  const int lane = tid & 63;

  // ---- WT staging: 16 blocks x 256 threads x 4 elems = 16384 ----
  const int gidx = blockIdx.x * 256 + tid;
#pragma unroll
  for (int j = 0; j < 4; ++j) {
    int o = gidx * 4 + j;            // ((t*2+i)*64 + e)*64 + k
    int k = o & 63;
    int e = (o >> 6) & 63;
    int ti = o >> 12;                // t*2+i
    ws_WT[o] = (bf16_t)tw[(ti * 64 + k) * 64 + e];
  }

  // ---- attention columns: 128 tasks (t,g) over 64 waves, 2 each ----
  const int wg = blockIdx.x * 4 + (tid >> 6);  // 0..63
  const int f = lane;
  const bool fv = (f < NFEAT);
  for (int i = 0; i < 2; ++i) {
    int col = wg * 2 + i;            // 0..127
    int t = col >> 6, g = col & 63;
    float val = 0.f;
    if (fv && g < NFEAT) {
      float a0 = masker[((t * 3 + 0) * NFEAT + f) * NFEAT + g];
      float a1 = masker[((t * 3 + 1) * NFEAT + f) * NFEAT + g];
      float a2 = masker[((t * 3 + 2) * NFEAT + f) * NFEAT + g];
      float prod = a0 * a1 * a2;
      val = prod > 0.f ? prod : 0.f;            // relu
    }
    float s = val;
    for (int off = 32; off > 0; off >>= 1) s += __shfl_xor(s, off);
    float mean = s / (float)NFEAT;
    float d = fv ? (val - mean) : 0.f;
    float v2 = d * d;
    for (int off = 32; off > 0; off >>= 1) v2 += __shfl_xor(v2, off);
    float var = v2 / (float)NFEAT;
    float lw = fv ? ln_w[f] : 0.f;
    float lb = fv ? ln_b[f] : 0.f;
    float aln = d * rsqrtf(var + LN_EPS) * lw + lb;
    float logit = aln + ((val != 0.f) ? 0.f : NEG_INF_C) + ((f == g) ? 1.f : 0.f);
    if (!fv) logit = -3.0e38f;
    float mx = logit;
    for (int off = 32; off > 0; off >>= 1) mx = fmaxf(mx, __shfl_xor(mx, off));
    float ex = fv ? expf(logit - mx) : 0.f;
    float se = ex;
    for (int off = 32; off > 0; off >>= 1) se += __shfl_xor(se, off);
    float attn = (fv && g < NFEAT && val != 0.f) ? (ex / se) : 0.f;
    ws_attnT[(t * 64 + g) * 64 + f] = (bf16_t)attn;
  }
}

// One block handles NB consecutive batch elements. 4 waves; wave w owns rows 16w..16w+15.
// t=0/t=1 merged: feat loaded once, 2 barriers per b (was 4), invariants in registers.
__global__ __launch_bounds__(256) void main_kernel(
    const float* __restrict__ feat, const float* __restrict__ tb,
    const float* __restrict__ gw, const float* __restrict__ gb,
    const bf16_t* __restrict__ ws_attnT, const bf16_t* __restrict__ ws_WT,
    float* __restrict__ out)
{
  __shared__ bf16_t sPT[2][64 * 72];   // P^T[e][f'] per t, pitch 72
  __shared__ float sLog[2][4];

  const int tid = threadIdx.x;
  const int w = tid >> 6;
  const int lane = tid & 63;
  const int l16 = lane & 15;
  const int lquad = lane >> 4;
  const int m0 = w * 16;

  // ---- block-invariant register state ----
  bf16x8 aat[2][2];                    // attnT A-frags (rows g = m0+l16)
#pragma unroll
  for (int t = 0; t < 2; ++t)
#pragma unroll
    for (int kc = 0; kc < 2; ++kc)
      aat[t][kc] = *(const bf16x8*)(ws_attnT + (t * 64 + m0 + l16) * 64 + kc * 32 + lquad * 8);

  float tbr[2][4][4], gwr[4][4];
#pragma unroll
  for (int n = 0; n < 4; ++n) {
    int e = n * 16 + l16;
#pragma unroll
    for (int r = 0; r < 4; ++r) {
      int f = m0 + lquad * 4 + r;
      bool v = (f < NFEAT);
      gwr[n][r]    = v ? gw[f * 64 + e] : 0.f;
      tbr[0][n][r] = v ? tb[(0 * NFEAT + f) * 64 + e] : 0.f;
      tbr[1][n][r] = v ? tb[(1 * NFEAT + f) * 64 + e] : 0.f;
    }
  }
  const float gbv = gb[0];
  const int fA = m0 + l16;

  for (int ib = 0; ib < NB; ++ib) {
    const int b = blockIdx.x * NB + ib;
    const float* featb = feat + b * (NFEAT * EDIM);

    // ---- feat A-frags (loaded once, shared by all 4 accumulator streams) ----
    bf16x8 a[2];
#pragma unroll
    for (int kc = 0; kc < 2; ++kc) {
#pragma unroll
      for (int j = 0; j < 8; ++j) a[kc][j] = (bf16_t)0.f;
      if (fA < NFEAT) {
        const float4* pa = (const float4*)(featb + fA * 64 + kc * 32 + lquad * 8);
        float4 x0 = pa[0], x1 = pa[1];
        a[kc][0] = (bf16_t)x0.x; a[kc][1] = (bf16_t)x0.y; a[kc][2] = (bf16_t)x0.z; a[kc][3] = (bf16_t)x0.w;
        a[kc][4] = (bf16_t)x1.x; a[kc][5] = (bf16_t)x1.y; a[kc][6] = (bf16_t)x1.z; a[kc][7] = (bf16_t)x1.w;
      }
    }

    f32x4 accH[2][4], accP[2][4];
#pragma unroll
    for (int t = 0; t < 2; ++t)
#pragma unroll
      for (int n = 0; n < 4; ++n) {
        accH[t][n] = (f32x4){0.f, 0.f, 0.f, 0.f};
        accP[t][n] = (f32x4){0.f, 0.f, 0.f, 0.f};
      }

    // ---- pass 1: accH[t] = F@W1_t, accP[t] = F@W2_t  (4 independent streams) ----
#pragma unroll
    for (int kc = 0; kc < 2; ++kc) {
#pragma unroll
      for (int n = 0; n < 4; ++n) {
        const int bo = (n * 16 + l16) * 64 + kc * 32 + lquad * 8;
        const bf16x8 b10 = *(const bf16x8*)(ws_WT + (0 * 64) * 64 + bo);  // t0 W1
        const bf16x8 b20 = *(const bf16x8*)(ws_WT + (1 * 64) * 64 + bo);  // t0 W2
        const bf16x8 b11 = *(const bf16x8*)(ws_WT + (2 * 64) * 64 + bo);  // t1 W1
        const bf16x8 b21 = *(const bf16x8*)(ws_WT + (3 * 64) * 64 + bo);  // t1 W2
        accH[0][n] = __builtin_amdgcn_mfma_f32_16x16x32_bf16(a[kc], b10, accH[0][n], 0, 0, 0);
        accP[0][n] = __builtin_amdgcn_mfma_f32_16x16x32_bf16(a[kc], b20, accP[0][n], 0, 0, 0);
        accH[1][n] = __builtin_amdgcn_mfma_f32_16x16x32_bf16(a[kc], b11, accH[1][n], 0, 0, 0);
        accP[1][n] = __builtin_amdgcn_mfma_f32_16x16x32_bf16(a[kc], b21, accP[1][n], 0, 0, 0);
      }
    }

    // ---- write both P^T tiles to LDS ----
#pragma unroll
    for (int t = 0; t < 2; ++t)
#pragma unroll
      for (int n = 0; n < 4; ++n) {
        bf16x4 pv;
        pv[0] = (bf16_t)accP[t][n][0]; pv[1] = (bf16_t)accP[t][n][1];
        pv[2] = (bf16_t)accP[t][n][2]; pv[3] = (bf16_t)accP[t][n][3];
        *(bf16x4*)&sPT[t][(n * 16 + l16) * 72 + m0 + lquad * 4] = pv;
      }
    __syncthreads();

    // ---- pass 2: accH[t] += attnT_t @ P_t ----
#pragma unroll
    for (int kc = 0; kc < 2; ++kc) {
#pragma unroll
      for (int n = 0; n < 4; ++n) {
        const int so = (n * 16 + l16) * 72 + kc * 32 + lquad * 8;
        const bf16x8 bp0 = *(const bf16x8*)(&sPT[0][so]);
        const bf16x8 bp1 = *(const bf16x8*)(&sPT[1][so]);
        accH[0][n] = __builtin_amdgcn_mfma_f32_16x16x32_bf16(aat[0][kc], bp0, accH[0][n], 0, 0, 0);
        accH[1][n] = __builtin_amdgcn_mfma_f32_16x16x32_bf16(aat[1][kc], bp1, accH[1][n], 0, 0, 0);
      }
    }

    // ---- + transform_b, gate-logit partials (both t) ----
    float p0 = 0.f, p1 = 0.f;
#pragma unroll
    for (int n = 0; n < 4; ++n)
#pragma unroll
      for (int r = 0; r < 4; ++r) {
        float h0 = accH[0][n][r] + tbr[0][n][r];
        float h1 = accH[1][n][r] + tbr[1][n][r];
        accH[0][n][r] = h0; accH[1][n][r] = h1;
        p0 += h0 * gwr[n][r];
        p1 += h1 * gwr[n][r];
      }
#pragma unroll
    for (int off = 32; off > 0; off >>= 1) {
      p0 += __shfl_xor(p0, off);
      p1 += __shfl_xor(p1, off);
    }
    if (lane == 0) { sLog[0][w] = p0; sLog[1][w] = p1; }
    __syncthreads();   // sLog visible; also fences sPT reads before next iter's writes

    // ---- gate softmax over T=2, weighted sum, store ----
    const float g0 = sLog[0][0] + sLog[0][1] + sLog[0][2] + sLog[0][3] + gbv;
    const float g1 = sLog[1][0] + sLog[1][1] + sLog[1][2] + sLog[1][3] + gbv;
    const float mx = fmaxf(g0, g1);
    const float e0 = expf(g0 - mx), e1 = expf(g1 - mx);
    const float inv = 1.f / (e0 + e1);
    const float ga0 = e0 * inv, ga1 = e1 * inv;

    float* outb = out + b * (NFEAT * EDIM);
#pragma unroll
    for (int n = 0; n < 4; ++n) {
      int e = n * 16 + l16;
#pragma unroll
      for (int r = 0; r < 4; ++r) {
        int f = m0 + lquad * 4 + r;
        if (f < NFEAT)
          outb[f * 64 + e] = ga0 * accH[0][n][r] + ga1 * accH[1][n][r];
      }
    }
  }
}

extern "C" void kernel_launch(void* const* d_in, const int* in_sizes, int n_in,
                              void* d_out, int out_size, void* d_ws, size_t ws_size,
                              hipStream_t stream) {
  const float* feat   = (const float*)d_in[0];
  const float* masker = (const float*)d_in[1];
  const float* tw     = (const float*)d_in[2];
  const float* tb     = (const float*)d_in[3];
  const float* lnw    = (const float*)d_in[4];
  const float* lnb    = (const float*)d_in[5];
  const float* gw     = (const float*)d_in[6];
  const float* gb     = (const float*)d_in[7];
  float* out = (float*)d_out;

  bf16_t* ws_attnT = (bf16_t*)d_ws;                 // 2*64*64 = 8192 elems
  bf16_t* ws_WT    = ws_attnT + 2 * 64 * 64;        // 2*2*64*64 = 16384 elems

  prep_kernel<<<16, 256, 0, stream>>>(masker, lnw, lnb, tw, ws_attnT, ws_WT);
  main_kernel<<<4096 / NB, 256, 0, stream>>>(feat, tb, gw, gb, ws_attnT, ws_WT, out);
}